// Round 20
// baseline (216.365 us; speedup 1.0000x reference)
//
#include <hip/hip_runtime.h>

// MonarchLinear collapsed to ONE dense GEMM (round 20).
//   out[b, s*68+l] = sum_{r,p} x[b, r*68+p] * L[r,l,p] * R[l,s,r] + bias
//   => W[j][c] = L[r][l][p]*R[l][s][r]  (j=s*68+l<4608, c=r*68+p<256)
//   => out = x @ W^T + bias : GEMM M=16384, N=4608, K=256, bf16 MFMA.
// Kills the unexplained ~45us "phase A" plateau (r13-r19) entirely: compute is
// ~5us of MFMA/SIMD, stores flow continuously at the 46.6us write roofline.
// Main kernel: 256 blocks x 256thr; block = 64 tokens; A (x) in 128 VGPR bf16
// frags (converted in-prologue, no x pack kernel); Wb staged via LDS in 36
// double-buffered 128-row panels (132KB LDS, row pad 264 -> 2-way-free b128),
// T14 async-split staging; 4 waves split j; M-reuse=4 -> LDS pipe ~11us.

typedef float f4 __attribute__((ext_vector_type(4)));
typedef short s8v __attribute__((ext_vector_type(8)));   // 8 bf16 = 4 VGPR (guide §3)

namespace {
constexpr int MM    = 68;
constexpr int IN_D  = 256;
constexpr int OUT_D = 4608;
constexpr int BM    = 64;            // tokens per block
constexpr int NTH   = 256;
constexpr int PJ    = 128;           // panel j-rows
constexpr int WROW  = 264;           // padded LDS row (ushorts): 528B = 2-way free
constexpr int NP    = OUT_D / PJ;    // 36 panels
}

__device__ __forceinline__ unsigned short f2bf(float f) {
  unsigned int u = __float_as_uint(f);
  u += 0x7FFFu + ((u >> 16) & 1u);   // round-to-nearest-even
  return (unsigned short)(u >> 16);
}

// ---------------- pack: Wb[j][c] = bf16(L[r][l][p] * R[l][s][r]) ----------------
__global__ __launch_bounds__(NTH, 1)
void pack_w(const float* __restrict__ L, const float* __restrict__ R,
            unsigned short* __restrict__ Wb)
{
  const int j  = blockIdx.x * 8 + (threadIdx.x >> 5);   // 8 j-rows per block
  const int c0 = (threadIdx.x & 31) * 8;
  const int s  = j / MM;
  const int l  = j - s * MM;
  unsigned int h[4];
#pragma unroll
  for (int i2 = 0; i2 < 4; ++i2) {
    unsigned int lo, hi;
#pragma unroll
    for (int k = 0; k < 2; ++k) {
      int c = c0 + i2 * 2 + k;
      int r = c / MM, p = c - r * MM;
      float w = L[(r * MM + l) * MM + p] * R[(l * MM + s) * MM + r];
      if (k == 0) lo = f2bf(w); else hi = f2bf(w);
    }
    h[i2] = lo | (hi << 16);
  }
  uint4 v; v.x = h[0]; v.y = h[1]; v.z = h[2]; v.w = h[3];
  *(uint4*)(Wb + (size_t)j * IN_D + c0) = v;
}

// ---------------- main GEMM: out = x @ Wb^T + bias ----------------
__global__ __launch_bounds__(NTH)
void mono_gemm(const float* __restrict__ x, const unsigned short* __restrict__ Wb,
               const float* __restrict__ bias, float* __restrict__ out)
{
  __shared__ unsigned short wsm[2][PJ][WROW];   // 135,168 B
  const int tid  = threadIdx.x;
  const int lane = tid & 63;
  const int wv   = tid >> 6;           // wave 0..3 (j-splitter)
  const int lrow = lane & 15;          // A-row / B-col / D-col lane index
  const int lgrp = lane >> 4;          // 0..3
  const long tb  = (long)blockIdx.x * BM;

  // ---- stage panel 0 (load+write immediately; prologue covers latency) ----
  uint4 stg[16];
  {
    const unsigned short* src = Wb;    // panel 0
#pragma unroll
    for (int k = 0; k < 16; ++k) {
      int idx = k * NTH + tid;         // 0..4095 = 128 rows x 32 cols
      stg[k] = *(const uint4*)(src + (idx >> 5) * IN_D + (idx & 31) * 8);
    }
#pragma unroll
    for (int k = 0; k < 16; ++k) {
      int idx = k * NTH + tid;
      *(uint4*)(&wsm[0][idx >> 5][(idx & 31) * 8]) = stg[k];
    }
  }

  // ---- A prologue: 64 tokens x K=256 as bf16 frags in registers (128 VGPR) ----
  // MFMA A layout: lane holds A[row=lane&15][k=(lane>>4)*8 + 0..7] per K-step.
  s8v afr[4][8];
#pragma unroll
  for (int mt = 0; mt < 4; ++mt) {
#pragma unroll
    for (int ks = 0; ks < 8; ++ks) {
      const float* xp = x + (tb + mt * 16 + lrow) * IN_D + ks * 32 + lgrp * 8;
      f4 a = *(const f4*)(xp);
      f4 b = *(const f4*)(xp + 4);
      s8v t;
      t[0] = (short)f2bf(a.x); t[1] = (short)f2bf(a.y);
      t[2] = (short)f2bf(a.z); t[3] = (short)f2bf(a.w);
      t[4] = (short)f2bf(b.x); t[5] = (short)f2bf(b.y);
      t[6] = (short)f2bf(b.z); t[7] = (short)f2bf(b.w);
      afr[mt][ks] = t;
    }
  }

#pragma unroll 1
  for (int p = 0; p < NP; ++p) {
    __syncthreads();                               // panel p visible; buf (p+1)&1 free
    // ---- T14 async-split: issue next panel's loads now, write after compute ----
    if (p + 1 < NP) {
      const unsigned short* src = Wb + (size_t)(p + 1) * PJ * IN_D;
#pragma unroll
      for (int k = 0; k < 16; ++k) {
        int idx = k * NTH + tid;
        stg[k] = *(const uint4*)(src + (idx >> 5) * IN_D + (idx & 31) * 8);
      }
    }

    // ---- compute panel p: wave wv owns j-local [wv*32, wv*32+32) ----
    const unsigned short* buf = &wsm[p & 1][0][0];
#pragma unroll
    for (int cj = 0; cj < 2; ++cj) {
      const int jloc = wv * 32 + cj * 16;
      const int jg   = p * PJ + jloc + lrow;       // this lane's output column
      f4 acc0 = {0.f,0.f,0.f,0.f}, acc1 = {0.f,0.f,0.f,0.f};
      f4 acc2 = {0.f,0.f,0.f,0.f}, acc3 = {0.f,0.f,0.f,0.f};
#pragma unroll
      for (int ks = 0; ks < 8; ++ks) {
        s8v bf = *(const s8v*)(buf + (jloc + lrow) * WROW + ks * 32 + lgrp * 8);
        acc0 = __builtin_amdgcn_mfma_f32_16x16x32_bf16(afr[0][ks], bf, acc0, 0, 0, 0);
        acc1 = __builtin_amdgcn_mfma_f32_16x16x32_bf16(afr[1][ks], bf, acc1, 0, 0, 0);
        acc2 = __builtin_amdgcn_mfma_f32_16x16x32_bf16(afr[2][ks], bf, acc2, 0, 0, 0);
        acc3 = __builtin_amdgcn_mfma_f32_16x16x32_bf16(afr[3][ks], bf, acc3, 0, 0, 0);
      }
      const float bv = bias[jg];
      float* ob = out + tb * OUT_D + jg;
      // D layout (m89): col = lane&15, row = (lane>>4)*4 + q
#pragma unroll
      for (int q = 0; q < 4; ++q) {
        ob[(size_t)(0 * 16 + lgrp * 4 + q) * OUT_D] = acc0[q] + bv;
        ob[(size_t)(1 * 16 + lgrp * 4 + q) * OUT_D] = acc1[q] + bv;
        ob[(size_t)(2 * 16 + lgrp * 4 + q) * OUT_D] = acc2[q] + bv;
        ob[(size_t)(3 * 16 + lgrp * 4 + q) * OUT_D] = acc3[q] + bv;
      }
    }

    // ---- write next panel into the other buffer ----
    if (p + 1 < NP) {
#pragma unroll
      for (int k = 0; k < 16; ++k) {
        int idx = k * NTH + tid;
        *(uint4*)(&wsm[(p + 1) & 1][idx >> 5][(idx & 31) * 8]) = stg[k];
      }
    }
  }
}

// ---------------- fallback (ws too small): r13 fused fp32 kernel ----------------
typedef float f4f __attribute__((ext_vector_type(4)));
namespace {
constexpr int TTF  = 16;
constexpr int XROW = IN_D + 4;
constexpr int TPAD = 4 * MM + 4;
}
template <int P4M>
__device__ __forceinline__ void phaseA_f(const float* xls, const float* Lrow0, float* t1w)
{
  float acc[17];
#pragma unroll
  for (int li = 0; li < 17; ++li) acc[li] = 0.f;
#pragma unroll 1
  for (int p4 = 0; p4 < P4M; ++p4) {
    f4f xv = *(const f4f*)(xls + 4 * p4);
    f4f Lv[17];
#pragma unroll
    for (int li = 0; li < 17; ++li) Lv[li] = *(const f4f*)(Lrow0 + (size_t)li * MM + 4 * p4);
#pragma unroll
    for (int li = 0; li < 17; ++li) {
      acc[li] = fmaf(xv.x, Lv[li].x, acc[li]); acc[li] = fmaf(xv.y, Lv[li].y, acc[li]);
      acc[li] = fmaf(xv.z, Lv[li].z, acc[li]); acc[li] = fmaf(xv.w, Lv[li].w, acc[li]);
    }
  }
#pragma unroll
  for (int li = 0; li < 17; ++li) t1w[li] = acc[li];
}
__global__ __launch_bounds__(NTH, 4)
void monarch_fused(const float* __restrict__ x, const float* __restrict__ L,
                   const float* __restrict__ R, const float* __restrict__ bias,
                   float* __restrict__ out)
{
  __shared__ float xs[TTF * XROW];
  __shared__ float t1s[TTF * TPAD];
  const int tid = threadIdx.x;
  const long tb = (long)blockIdx.x * TTF;
#pragma unroll
  for (int k = 0; k < (TTF * IN_D / 4) / NTH; ++k) {
    int i = k * NTH + tid; int tok = i >> 6; int pos = i & 63;
    *(f4f*)(&xs[tok * XROW + 4 * pos]) = *(const f4f*)(x + (tb + tok) * IN_D + 4 * pos);
  }
  __syncthreads();
  {
    const int tok = tid & 15; const int seg = tid >> 4;
    const int r = seg >> 2; const int lq = seg & 3;
    const float* xls = &xs[tok * XROW + r * MM];
    const float* Lrow0 = L + (size_t)(r * MM + lq * 17) * MM;
    float* t1w = &t1s[tok * TPAD + r * MM + lq * 17];
    if (r < 3) phaseA_f<17>(xls, Lrow0, t1w); else phaseA_f<13>(xls, Lrow0, t1w);
  }
  __syncthreads();
  {
    const int g = tid / 17; const int m = tid - g * 17; const int l4 = 4 * m;
#pragma unroll 1
    for (int j = 0; j < 5; ++j) {
      const int s = g + 15 * j;
      const bool act = (tid < 255) && (s < MM) && (s < MM - 1 || m < 13);
      const int scol = s * MM + l4;
      f4f R0, R1, R2, R3, bv;
      if (act) {
        R0 = *(const f4f*)(R + (size_t)(l4 + 0) * (MM * MM) + (size_t)s * MM);
        R1 = *(const f4f*)(R + (size_t)(l4 + 1) * (MM * MM) + (size_t)s * MM);
        R2 = *(const f4f*)(R + (size_t)(l4 + 2) * (MM * MM) + (size_t)s * MM);
        R3 = *(const f4f*)(R + (size_t)(l4 + 3) * (MM * MM) + (size_t)s * MM);
        bv = *(const f4f*)(bias + scol);
      }
#pragma unroll 2
      for (int t = 0; t < TTF; ++t) {
        if (act) {
          const float* t1p = t1s + t * TPAD + l4;
          f4f a0 = *(const f4f*)(t1p); f4f a1 = *(const f4f*)(t1p + MM);
          f4f a2 = *(const f4f*)(t1p + 2 * MM); f4f a3 = *(const f4f*)(t1p + 3 * MM);
          f4f o;
          o.x = fmaf(a3.x, R0.w, fmaf(a2.x, R0.z, fmaf(a1.x, R0.y, fmaf(a0.x, R0.x, bv.x))));
          o.y = fmaf(a3.y, R1.w, fmaf(a2.y, R1.z, fmaf(a1.y, R1.y, fmaf(a0.y, R1.x, bv.y))));
          o.z = fmaf(a3.z, R2.w, fmaf(a2.z, R2.z, fmaf(a1.z, R2.y, fmaf(a0.z, R2.x, bv.z))));
          o.w = fmaf(a3.w, R3.w, fmaf(a2.w, R3.z, fmaf(a1.w, R3.y, fmaf(a0.w, R3.x, bv.w))));
          *(f4f*)(out + (tb + t) * OUT_D + scol) = o;
        }
      }
    }
  }
}

extern "C" void kernel_launch(void* const* d_in, const int* in_sizes, int n_in,
                              void* d_out, int out_size, void* d_ws, size_t ws_size,
                              hipStream_t stream) {
  const float* x    = (const float*)d_in[0];
  const float* L    = (const float*)d_in[1];
  const float* R    = (const float*)d_in[2];
  const float* bias = (const float*)d_in[3];
  float* out = (float*)d_out;

  const int ntok = in_sizes[0] / IN_D;                       // 16384
  const size_t wb_bytes = (size_t)OUT_D * IN_D * sizeof(unsigned short);  // 2.36 MB

  if (ws_size >= wb_bytes) {
    unsigned short* Wb = (unsigned short*)d_ws;
    pack_w<<<OUT_D / 8, NTH, 0, stream>>>(L, R, Wb);
    mono_gemm<<<ntok / BM, NTH, 0, stream>>>(x, Wb, bias, out);
  } else {
    monarch_fused<<<ntok / TTF, NTH, 0, stream>>>(x, L, R, bias, out);
  }
}

// Round 21
// 111.049 us; speedup vs baseline: 1.9484x; 1.9484x over previous
//
#include <hip/hip_runtime.h>

// MonarchLinear as one dense bf16-MFMA GEMM (round 21).
//   W[j][k] = L[r][l][p]*R[l][s][r] (j=s*68+l, k=r*68+p<256); out = x @ W^T + bias.
// r20 proved correctness (absmax 2.4e-4) but lost to: WRITE 858MB (2.75x, partial-
// line scattered epilogue), 1 block/CU (135KB LDS), W-LDS bank conflicts. Fixes:
//  - pack_w2: W pre-packed in MFMA B-frag order -> main kernel B loads are
//    lane-contiguous 1KB uint4 reads from L2-resident 2.36MB (no W LDS at all).
//  - per-wave LDS transpose epilogue (18KB total): stores become full 128B-line
//    aligned 1KB-contiguous f4 writes (no amplification, no __syncthreads).
//  - grid 1024 = 512 token-tiles x 2 j-halves; launch_bounds(256,3): 3 blk/CU.

typedef float f4 __attribute__((ext_vector_type(4)));
typedef short s8v __attribute__((ext_vector_type(8)));   // 8 bf16 = 4 VGPR

namespace {
constexpr int MM    = 68;
constexpr int IN_D  = 256;
constexpr int OUT_D = 4608;
constexpr int NTH   = 256;
constexpr int BM    = 32;            // tokens per block (2 MFMA row-tiles)
constexpr int EPW   = 36;            // ep row stride (f32): 144B, 16B-aligned
}

__device__ __forceinline__ unsigned short f2bf(float f) {
  unsigned int u = __float_as_uint(f);
  u += 0x7FFFu + ((u >> 16) & 1u);   // RNE
  return (unsigned short)(u >> 16);
}

// ---------- pack: Wpk in MFMA B-frag order: frag g=(jc*8+ks), lane -> 16B ----------
// lane&15 -> j = jc*16+(lane&15); k = ks*32 + (lane>>4)*8 + e  (r20-proven layout)
__global__ __launch_bounds__(NTH, 1)
void pack_w2(const float* __restrict__ L, const float* __restrict__ R,
             unsigned short* __restrict__ Wpk)
{
  const int g    = blockIdx.x * 4 + (threadIdx.x >> 6);   // 0..2303
  const int lane = threadIdx.x & 63;
  const int jc   = g >> 3;
  const int ks   = g & 7;
  const int j    = jc * 16 + (lane & 15);
  const int s    = j / MM;
  const int l    = j - s * MM;
  const int k0   = ks * 32 + (lane >> 4) * 8;
  unsigned int h[4];
#pragma unroll
  for (int i2 = 0; i2 < 4; ++i2) {
    unsigned int w2[2];
#pragma unroll
    for (int e = 0; e < 2; ++e) {
      int k = k0 + i2 * 2 + e;
      int r = k / MM, p = k - r * MM;
      float w = L[(r * MM + l) * MM + p] * R[(l * MM + s) * MM + r];
      w2[e] = f2bf(w);
    }
    h[i2] = w2[0] | (w2[1] << 16);
  }
  uint4 v; v.x = h[0]; v.y = h[1]; v.z = h[2]; v.w = h[3];
  *(uint4*)(Wpk + ((size_t)g * 64 + lane) * 8) = v;
}

// ---------------- main GEMM: out = x @ W^T + bias ----------------
__global__ __launch_bounds__(NTH, 3)
void mono_gemm2(const float* __restrict__ x, const unsigned short* __restrict__ Wpk,
                const float* __restrict__ bias, float* __restrict__ out)
{
  __shared__ float ep[4][BM][EPW];     // per-WAVE transpose slices, 18,432 B
  const int tid  = threadIdx.x;
  const int lane = tid & 63;
  const int wv   = tid >> 6;
  const int lrow = lane & 15;
  const int lgrp = lane >> 4;
  const int tile = blockIdx.x >> 1;
  const int jh   = blockIdx.x & 1;     // j half: 0 -> [0,2304), 1 -> [2304,4608)
  const long tb  = (long)tile * BM;

  // ---- A prologue: 32 tokens x K=256 bf16 frags (64 VGPR), r20-proven layout ----
  s8v afr[2][8];
#pragma unroll
  for (int mt = 0; mt < 2; ++mt) {
#pragma unroll
    for (int ks = 0; ks < 8; ++ks) {
      const float* xp = x + (tb + mt * 16 + lrow) * IN_D + ks * 32 + lgrp * 8;
      f4 a = *(const f4*)(xp);
      f4 b = *(const f4*)(xp + 4);
      s8v t;
      t[0] = (short)f2bf(a.x); t[1] = (short)f2bf(a.y);
      t[2] = (short)f2bf(a.z); t[3] = (short)f2bf(a.w);
      t[4] = (short)f2bf(b.x); t[5] = (short)f2bf(b.y);
      t[6] = (short)f2bf(b.z); t[7] = (short)f2bf(b.w);
      afr[mt][ks] = t;
    }
  }

  float (*eps)[EPW] = ep[wv];          // this wave's private slice — no barriers

#pragma unroll 1
  for (int i = 0; i < 18; ++i) {
    const int j0 = ((i * 4 + wv) << 5) + jh * 2304;   // 32-j chunk, 128B-aligned
    // ---- two 16-j MFMA tiles ----
#pragma unroll
    for (int c = 0; c < 2; ++c) {
      const int jcIdx = (j0 >> 4) + c;
      uint4 bfr[8];
#pragma unroll
      for (int ks = 0; ks < 8; ++ks)   // lane-contiguous 1KB loads, L2-hot
        bfr[ks] = *(const uint4*)(Wpk + (((size_t)jcIdx * 8 + ks) * 64 + lane) * 8);
      f4 a0 = {0.f, 0.f, 0.f, 0.f}, a1 = {0.f, 0.f, 0.f, 0.f};
#pragma unroll
      for (int ks = 0; ks < 8; ++ks) {
        s8v bf = *(s8v*)&bfr[ks];
        a0 = __builtin_amdgcn_mfma_f32_16x16x32_bf16(afr[0][ks], bf, a0, 0, 0, 0);
        a1 = __builtin_amdgcn_mfma_f32_16x16x32_bf16(afr[1][ks], bf, a1, 0, 0, 0);
      }
      // D layout: col=lane&15 (j), row=(lane>>4)*4+q (token) — write transposed
#pragma unroll
      for (int q = 0; q < 4; ++q) {
        eps[lgrp * 4 + q][c * 16 + lrow]      = a0[q];   // 2-way banks: free
        eps[16 + lgrp * 4 + q][c * 16 + lrow] = a1[q];
      }
    }
    // ---- coalesced epilogue: full 128B-line stores ----
    const f4 bv = *(const f4*)(bias + j0 + (lane & 7) * 4);
#pragma unroll
    for (int sw = 0; sw < 4; ++sw) {
      const int rr = sw * 8 + (lane >> 3);
      f4 v = *(const f4*)(&eps[rr][(lane & 7) * 4]);
      f4 o;
      o.x = v.x + bv.x; o.y = v.y + bv.y; o.z = v.z + bv.z; o.w = v.w + bv.w;
      *(f4*)(out + (tb + rr) * OUT_D + j0 + (lane & 7) * 4) = o;
    }
  }
}

// ---------------- fallback (ws too small): r13 fused fp32 kernel ----------------
namespace {
constexpr int TTF  = 16;
constexpr int XROW = IN_D + 4;
constexpr int TPAD = 4 * MM + 4;
}
template <int P4M>
__device__ __forceinline__ void phaseA_f(const float* xls, const float* Lrow0, float* t1w)
{
  float acc[17];
#pragma unroll
  for (int li = 0; li < 17; ++li) acc[li] = 0.f;
#pragma unroll 1
  for (int p4 = 0; p4 < P4M; ++p4) {
    f4 xv = *(const f4*)(xls + 4 * p4);
    f4 Lv[17];
#pragma unroll
    for (int li = 0; li < 17; ++li) Lv[li] = *(const f4*)(Lrow0 + (size_t)li * MM + 4 * p4);
#pragma unroll
    for (int li = 0; li < 17; ++li) {
      acc[li] = fmaf(xv.x, Lv[li].x, acc[li]); acc[li] = fmaf(xv.y, Lv[li].y, acc[li]);
      acc[li] = fmaf(xv.z, Lv[li].z, acc[li]); acc[li] = fmaf(xv.w, Lv[li].w, acc[li]);
    }
  }
#pragma unroll
  for (int li = 0; li < 17; ++li) t1w[li] = acc[li];
}
__global__ __launch_bounds__(NTH, 4)
void monarch_fused(const float* __restrict__ x, const float* __restrict__ L,
                   const float* __restrict__ R, const float* __restrict__ bias,
                   float* __restrict__ out)
{
  __shared__ float xs[TTF * XROW];
  __shared__ float t1s[TTF * TPAD];
  const int tid = threadIdx.x;
  const long tb = (long)blockIdx.x * TTF;
#pragma unroll
  for (int k = 0; k < (TTF * IN_D / 4) / NTH; ++k) {
    int i = k * NTH + tid; int tok = i >> 6; int pos = i & 63;
    *(f4*)(&xs[tok * XROW + 4 * pos]) = *(const f4*)(x + (tb + tok) * IN_D + 4 * pos);
  }
  __syncthreads();
  {
    const int tok = tid & 15; const int seg = tid >> 4;
    const int r = seg >> 2; const int lq = seg & 3;
    const float* xls = &xs[tok * XROW + r * MM];
    const float* Lrow0 = L + (size_t)(r * MM + lq * 17) * MM;
    float* t1w = &t1s[tok * TPAD + r * MM + lq * 17];
    if (r < 3) phaseA_f<17>(xls, Lrow0, t1w); else phaseA_f<13>(xls, Lrow0, t1w);
  }
  __syncthreads();
  {
    const int g = tid / 17; const int m = tid - g * 17; const int l4 = 4 * m;
#pragma unroll 1
    for (int j = 0; j < 5; ++j) {
      const int s = g + 15 * j;
      const bool act = (tid < 255) && (s < MM) && (s < MM - 1 || m < 13);
      const int scol = s * MM + l4;
      f4 R0, R1, R2, R3, bv;
      if (act) {
        R0 = *(const f4*)(R + (size_t)(l4 + 0) * (MM * MM) + (size_t)s * MM);
        R1 = *(const f4*)(R + (size_t)(l4 + 1) * (MM * MM) + (size_t)s * MM);
        R2 = *(const f4*)(R + (size_t)(l4 + 2) * (MM * MM) + (size_t)s * MM);
        R3 = *(const f4*)(R + (size_t)(l4 + 3) * (MM * MM) + (size_t)s * MM);
        bv = *(const f4*)(bias + scol);
      }
#pragma unroll 2
      for (int t = 0; t < TTF; ++t) {
        if (act) {
          const float* t1p = t1s + t * TPAD + l4;
          f4 a0 = *(const f4*)(t1p); f4 a1 = *(const f4*)(t1p + MM);
          f4 a2 = *(const f4*)(t1p + 2 * MM); f4 a3 = *(const f4*)(t1p + 3 * MM);
          f4 o;
          o.x = fmaf(a3.x, R0.w, fmaf(a2.x, R0.z, fmaf(a1.x, R0.y, fmaf(a0.x, R0.x, bv.x))));
          o.y = fmaf(a3.y, R1.w, fmaf(a2.y, R1.z, fmaf(a1.y, R1.y, fmaf(a0.y, R1.x, bv.y))));
          o.z = fmaf(a3.z, R2.w, fmaf(a2.z, R2.z, fmaf(a1.z, R2.y, fmaf(a0.z, R2.x, bv.z))));
          o.w = fmaf(a3.w, R3.w, fmaf(a2.w, R3.z, fmaf(a1.w, R3.y, fmaf(a0.w, R3.x, bv.w))));
          *(f4*)(out + (tb + t) * OUT_D + scol) = o;
        }
      }
    }
  }
}

extern "C" void kernel_launch(void* const* d_in, const int* in_sizes, int n_in,
                              void* d_out, int out_size, void* d_ws, size_t ws_size,
                              hipStream_t stream) {
  const float* x    = (const float*)d_in[0];
  const float* L    = (const float*)d_in[1];
  const float* R    = (const float*)d_in[2];
  const float* bias = (const float*)d_in[3];
  float* out = (float*)d_out;

  const int ntok = in_sizes[0] / IN_D;                       // 16384
  const size_t wb_bytes = (size_t)OUT_D * IN_D * sizeof(unsigned short);  // 2.36 MB

  if (ws_size >= wb_bytes) {
    unsigned short* Wpk = (unsigned short*)d_ws;
    pack_w2<<<576, NTH, 0, stream>>>(L, R, Wpk);             // 2304 frag-groups
    mono_gemm2<<<(ntok / BM) * 2, NTH, 0, stream>>>(x, Wpk, bias, out);
  } else {
    monarch_fused<<<ntok / TTF, NTH, 0, stream>>>(x, L, R, bias, out);
  }
}